// Round 1
// baseline (683.876 us; speedup 1.0000x reference)
//
#include <hip/hip_runtime.h>
#include <stdint.h>

#define AS1 __attribute__((address_space(1)))
#define AS3 __attribute__((address_space(3)))

typedef __bf16 bf16x8 __attribute__((ext_vector_type(8)));
typedef float  f32x4  __attribute__((ext_vector_type(4)));

// tanh(x) = 1 - 2/(exp(2x)+1); exact at +/-inf, ~1ulp-level fp32 error.
__device__ __forceinline__ float tanh_fast(float x){
    float e = __expf(2.0f * x);
    return 1.0f - 2.0f / (e + 1.0f);
}

__device__ __forceinline__ unsigned short f2bf(float f){
    unsigned int u = __float_as_uint(f);
    u = (u + 0x7fffu + ((u >> 16) & 1u)) >> 16;   // RNE
    return (unsigned short)u;
}

// ---------------- zero the scatter output region ----------------
__global__ void k_zero(float* __restrict__ out){
    int i = blockIdx.x * 256 + threadIdx.x;
    if (i < 80000) ((float4*)out)[i] = make_float4(0.f, 0.f, 0.f, 0.f);
}

// ---------------- deterministic compaction of active mask positions ----------------
__global__ void k_pairs(const float* __restrict__ ef, int* __restrict__ pairs){
    int b = blockIdx.x, tid = threadIdx.x;
    __shared__ int s_base, s_woff[4], s_wc[4];
    if (tid == 0) s_base = 0;
    __syncthreads();
    int lane = tid & 63, w = tid >> 6;
    for (int ch = 0; ch < 40; ++ch){
        int pos = ch * 256 + tid;
        bool valid = false;
        if (pos < 10000){
            int r = pos / 100, c = pos - (pos / 100) * 100;
            valid = ef[(size_t)b * 35956 + (size_t)(1 + r) * 356 + 256 + c] != 0.0f;
        }
        unsigned long long bal = __ballot(valid);
        if (lane == 0) s_wc[w] = __popcll(bal);
        __syncthreads();
        if (tid == 0){
            int r = s_base;
            for (int q = 0; q < 4; ++q){ s_woff[q] = r; r += s_wc[q]; }
            s_base = r;
        }
        __syncthreads();
        if (valid){
            int rank = __popcll(bal & ((1ull << lane) - 1ull));
            int o = s_woff[w] + rank;
            if (o < 5000) pairs[b * 5000 + o] = pos;
        }
        __syncthreads();
    }
}

// ---------------- aW1[256:768] -> bf16, transposed [s][col][k] ----------------
__global__ void k_w1t(const float* __restrict__ aW1, unsigned short* __restrict__ w1t){
    int tid = blockIdx.x * 256 + threadIdx.x;          // 65536 threads
    int k8 = tid & 31, c = (tid >> 5) & 1023, s = tid >> 15;
    const float* src = aW1 + (size_t)(256 + s * 256 + k8 * 8) * 1024 + c;
    unsigned int* dst = (unsigned int*)(w1t + (size_t)tid * 8);
#pragma unroll
    for (int jj = 0; jj < 4; ++jj){
        unsigned short lo = f2bf(src[(size_t)(2 * jj) * 1024]);
        unsigned short hi = f2bf(src[(size_t)(2 * jj + 1) * 1024]);
        dst[jj] = (unsigned int)lo | ((unsigned int)hi << 16);
    }
}

// ---------------- aW2 -> bf16 blocked into MFMA B-fragment order ----------------
// w2b element ((ct*32+kt)*64 + lane)*8 + j = aW2[kt*32 + (lane>>4)*8 + j][ct*16 + (lane&15)]
__global__ void k_w2b(const float* __restrict__ aW2, unsigned short* __restrict__ w2b){
    int tid = blockIdx.x * 256 + threadIdx.x;          // 131072 threads
    int lane = tid & 63, kt = (tid >> 6) & 31, ct = tid >> 11;
    int quad = lane >> 4, n = lane & 15;
    const float* src = aW2 + (size_t)(kt * 32 + quad * 8) * 1024 + ct * 16 + n;
    unsigned int* dst = (unsigned int*)(w2b + (size_t)tid * 8);
#pragma unroll
    for (int jj = 0; jj < 4; ++jj){
        unsigned short lo = f2bf(src[(size_t)(2 * jj) * 1024]);
        unsigned short hi = f2bf(src[(size_t)(2 * jj + 1) * 1024]);
        dst[jj] = (unsigned int)lo | ((unsigned int)hi << 16);
    }
}

// ---------------- g1[b][c] = g_b @ aW1[:256] + ab1 (fp32 exact) ----------------
__global__ void k_g1(const float* __restrict__ ef, const float* __restrict__ aW1,
                     const float* __restrict__ ab1, float* __restrict__ g1o){
    int b = blockIdx.x, t = threadIdx.x;
    __shared__ float gs[256];
    gs[t] = ef[(size_t)b * 35956 + t];
    __syncthreads();
    float a0 = 0.f, a1 = 0.f, a2 = 0.f, a3 = 0.f;
    for (int i = 0; i < 256; ++i){
        float gi = gs[i];
        const float* row = aW1 + (size_t)i * 1024;
        a0 += gi * row[t];       a1 += gi * row[t + 256];
        a2 += gi * row[t + 512]; a3 += gi * row[t + 768];
    }
    float* o = g1o + (size_t)b * 1024;
    o[t] = a0 + ab1[t];             o[t + 256] = a1 + ab1[t + 256];
    o[t + 512] = a2 + ab1[t + 512]; o[t + 768] = a3 + ab1[t + 768];
}

// ---------------- P{1,2}[b][node][c] = nodes_b @ aW1 slice (bf16 MFMA) ----------------
__global__ __launch_bounds__(256) void k_p(const float* __restrict__ ef,
        const unsigned short* __restrict__ w1t, float* __restrict__ P){
    __shared__ __align__(16) unsigned short an[112 * 264];
    int blk = blockIdx.x;
    int cb = blk & 15, s = (blk >> 4) & 1, b = blk >> 5;
    int t = threadIdx.x;
    for (int e = t; e < 25600; e += 256){            // stage nodes as bf16
        int row = e >> 8, col = e & 255;
        an[row * 264 + col] = f2bf(ef[(size_t)b * 35956 + (size_t)(1 + row) * 356 + col]);
    }
    for (int e = t; e < 3168; e += 256) an[26400 + e] = 0;  // zero pad rows 100..111
    __syncthreads();
    int w = t >> 6, lane = t & 63, quad = lane >> 4, n = lane & 15;
    int c = cb * 64 + w * 16 + n;
    f32x4 acc[7];
#pragma unroll
    for (int m = 0; m < 7; ++m){ f32x4 z = {0.f, 0.f, 0.f, 0.f}; acc[m] = z; }
    const bf16x8* wp = (const bf16x8*)(w1t + (size_t)(s * 1024 + c) * 256);
#pragma unroll
    for (int kt = 0; kt < 8; ++kt){
        bf16x8 bfr = wp[kt * 4 + quad];
#pragma unroll
        for (int m = 0; m < 7; ++m){
            const bf16x8* ap = (const bf16x8*)(an + (m * 16 + n) * 264 + kt * 32 + quad * 8);
            acc[m] = __builtin_amdgcn_mfma_f32_16x16x32_bf16(*ap, bfr, acc[m], 0, 0, 0);
        }
    }
    size_t base = (size_t)s * 3276800 + (size_t)b * 102400;
#pragma unroll
    for (int m = 0; m < 7; ++m){
        int r0 = m * 16 + quad * 4;
#pragma unroll
        for (int r = 0; r < 4; ++r){
            int row = r0 + r;
            if (row < 100) P[base + (size_t)row * 1024 + c] = acc[m][r];
        }
    }
}

// ---------------- value head (tiny, fp32) ----------------
__global__ void k_v(const float* __restrict__ ef,
                    const float* __restrict__ cW1, const float* __restrict__ cb1,
                    const float* __restrict__ cW2, const float* __restrict__ cb2,
                    const float* __restrict__ cW3, const float* __restrict__ cb3,
                    float* __restrict__ out){
    int b = blockIdx.x, t = threadIdx.x;
    __shared__ float gs[256], h1[512], h2[512], wred[4];
    gs[t] = ef[(size_t)b * 35956 + t];
    __syncthreads();
    for (int o = t; o < 512; o += 256){
        float a = cb1[o];
        for (int i = 0; i < 256; ++i) a += gs[i] * cW1[(size_t)i * 512 + o];
        h1[o] = tanh_fast(a);
    }
    __syncthreads();
    for (int o = t; o < 512; o += 256){
        float a = cb2[o];
        for (int i = 0; i < 512; ++i) a += h1[i] * cW2[(size_t)i * 512 + o];
        h2[o] = tanh_fast(a);
    }
    __syncthreads();
    float p = h2[t] * cW3[t] + h2[t + 256] * cW3[t + 256];
    for (int m = 32; m >= 1; m >>= 1) p += __shfl_xor(p, m);
    if ((t & 63) == 0) wred[t >> 6] = p;
    __syncthreads();
    if (t == 0) out[320000 + b] = wred[0] + wred[1] + wred[2] + wred[3] + cb3[0];
}

// ---------------- staging helper: one 32KB col-tile of blocked aW2 -> LDS ----------------
__device__ __forceinline__ void stage_ct(const unsigned short* __restrict__ w2b,
                                         unsigned short* dst, int ct, int w, int lane){
#if defined(__has_builtin) && __has_builtin(__builtin_amdgcn_global_load_lds)
    const unsigned short* src = w2b + (size_t)ct * 16384 + w * 4096 + lane * 8;
    unsigned short* d = dst + w * 4096;
#pragma unroll
    for (int i = 0; i < 8; ++i){
        __builtin_amdgcn_global_load_lds((AS1 void*)(src + i * 512),
                                         (AS3 void*)(d + i * 512), 16, 0, 0);
    }
#else
    const uint4* src = (const uint4*)(w2b + (size_t)ct * 16384 + w * 4096) + lane;
    uint4* d = (uint4*)(dst + w * 4096) + lane;
#pragma unroll
    for (int i = 0; i < 8; ++i) d[i * 64] = src[i * 64];
#endif
}

// ---------------- fused layer1-gather + layer2 GEMM + layer3 dot ----------------
__global__ __launch_bounds__(256, 2) void k_main(
    const int* __restrict__ pairs, const float* __restrict__ g1,
    const float* __restrict__ P1, const float* __restrict__ P2,
    const unsigned short* __restrict__ w2b, const float* __restrict__ ab2,
    const float* __restrict__ aW3, float* __restrict__ logits)
{
    __shared__ __align__(16) unsigned short wbuf[2][16384];   // 2 x 32KB
    int b = blockIdx.x / 79, tile = blockIdx.x % 79;
    int t = threadIdx.x, w = t >> 6, lane = t & 63, quad = lane >> 4, n = lane & 15;

    stage_ct(w2b, &wbuf[0][0], 0, w, lane);   // prefetch ct=0 during phase 1

    int grow = tile * 64 + w * 16 + n;        // this lane's pair row (A row m = n)
    int pidx = pairs[b * 5000 + (grow < 5000 ? grow : 4999)];
    int i1 = pidx / 100;
    int i2 = pidx - i1 * 100;
    const float* p1 = P1 + ((size_t)b * 100 + i1) * 1024;
    const float* p2 = P2 + ((size_t)b * 100 + i2) * 1024;
    const float* gg = g1 + (size_t)b * 1024;

    // phase 1: h row fragments in registers. af[kt] holds h[m=n][kt*32+quad*8 .. +8]
    bf16x8 af[32];
#pragma unroll
    for (int kt = 0; kt < 32; ++kt){
        int k0 = kt * 32 + quad * 8;
        const float4* A  = (const float4*)(p1 + k0);
        const float4* Bv = (const float4*)(p2 + k0);
        const float4* G  = (const float4*)(gg + k0);
        float4 a0 = A[0], a1 = A[1], b0 = Bv[0], b1 = Bv[1], c0 = G[0], c1 = G[1];
        bf16x8 f;
        f[0] = (__bf16)tanh_fast(a0.x + b0.x + c0.x);
        f[1] = (__bf16)tanh_fast(a0.y + b0.y + c0.y);
        f[2] = (__bf16)tanh_fast(a0.z + b0.z + c0.z);
        f[3] = (__bf16)tanh_fast(a0.w + b0.w + c0.w);
        f[4] = (__bf16)tanh_fast(a1.x + b1.x + c1.x);
        f[5] = (__bf16)tanh_fast(a1.y + b1.y + c1.y);
        f[6] = (__bf16)tanh_fast(a1.z + b1.z + c1.z);
        f[7] = (__bf16)tanh_fast(a1.w + b1.w + c1.w);
        af[kt] = f;
    }

    // phase 2: 64 col-tiles, double-buffered staging, fused bias+tanh+aW3 dot
    float prt0 = 0.f, prt1 = 0.f, prt2 = 0.f, prt3 = 0.f;
    for (int ct = 0; ct < 64; ++ct){
        int cur = ct & 1;
        __syncthreads();                           // wbuf[cur] staged for all waves
        if (ct < 63) stage_ct(w2b, &wbuf[cur ^ 1][0], ct + 1, w, lane);
        const bf16x8* bb = (const bf16x8*)(&wbuf[cur][0]);
        f32x4 acc0 = {0.f, 0.f, 0.f, 0.f}, acc1 = {0.f, 0.f, 0.f, 0.f};
#pragma unroll
        for (int kt = 0; kt < 32; kt += 2){
            bf16x8 w0 = bb[kt * 64 + lane];
            bf16x8 w1 = bb[(kt + 1) * 64 + lane];
            acc0 = __builtin_amdgcn_mfma_f32_16x16x32_bf16(af[kt],     w0, acc0, 0, 0, 0);
            acc1 = __builtin_amdgcn_mfma_f32_16x16x32_bf16(af[kt + 1], w1, acc1, 0, 0, 0);
        }
        int c = ct * 16 + n;
        float w3 = aW3[c], bias = ab2[c];
        prt0 += tanh_fast(acc0[0] + acc1[0] + bias) * w3;
        prt1 += tanh_fast(acc0[1] + acc1[1] + bias) * w3;
        prt2 += tanh_fast(acc0[2] + acc1[2] + bias) * w3;
        prt3 += tanh_fast(acc0[3] + acc1[3] + bias) * w3;
    }
    // reduce over the 16 cols held by lanes n=0..15 within each quad
    prt0 += __shfl_xor(prt0, 1); prt0 += __shfl_xor(prt0, 2); prt0 += __shfl_xor(prt0, 4); prt0 += __shfl_xor(prt0, 8);
    prt1 += __shfl_xor(prt1, 1); prt1 += __shfl_xor(prt1, 2); prt1 += __shfl_xor(prt1, 4); prt1 += __shfl_xor(prt1, 8);
    prt2 += __shfl_xor(prt2, 1); prt2 += __shfl_xor(prt2, 2); prt2 += __shfl_xor(prt2, 4); prt2 += __shfl_xor(prt2, 8);
    prt3 += __shfl_xor(prt3, 1); prt3 += __shfl_xor(prt3, 2); prt3 += __shfl_xor(prt3, 4); prt3 += __shfl_xor(prt3, 8);
    if (n == 0){
        int base = tile * 64 + w * 16 + quad * 4;
        if (base + 0 < 5000) logits[b * 5000 + base + 0] = prt0;
        if (base + 1 < 5000) logits[b * 5000 + base + 1] = prt1;
        if (base + 2 < 5000) logits[b * 5000 + base + 2] = prt2;
        if (base + 3 < 5000) logits[b * 5000 + base + 3] = prt3;
    }
}

// ---------------- softmax over K per batch + scatter into filled ----------------
__global__ void k_soft(const float* __restrict__ logits, const int* __restrict__ pairs,
                       float* __restrict__ out){
    int b = blockIdx.x, t = threadIdx.x;
    __shared__ float red[4];
    __shared__ float bmS, bsS;
    const float* lg = logits + b * 5000;
    float m = -1e30f;
    for (int j = t; j < 5000; j += 256) m = fmaxf(m, lg[j]);
    for (int s = 32; s >= 1; s >>= 1) m = fmaxf(m, __shfl_xor(m, s));
    if ((t & 63) == 0) red[t >> 6] = m;
    __syncthreads();
    if (t == 0) bmS = fmaxf(fmaxf(red[0], red[1]), fmaxf(red[2], red[3]));
    __syncthreads();
    float mm = bmS;
    float s = 0.f;
    for (int j = t; j < 5000; j += 256) s += __expf(lg[j] - mm);
    for (int k = 32; k >= 1; k >>= 1) s += __shfl_xor(s, k);
    if ((t & 63) == 0) red[t >> 6] = s;
    __syncthreads();
    if (t == 0) bsS = 1.0f / (red[0] + red[1] + red[2] + red[3]);
    __syncthreads();
    float inv = bsS;
    for (int j = t; j < 5000; j += 256){
        int pos = pairs[b * 5000 + j];
        out[(size_t)b * 10000 + pos] = __expf(lg[j] - mm) * inv;
    }
}

extern "C" void kernel_launch(void* const* d_in, const int* in_sizes, int n_in,
                              void* d_out, int out_size, void* d_ws, size_t ws_size,
                              hipStream_t stream) {
    (void)in_sizes; (void)n_in; (void)out_size; (void)ws_size;
    const float* ef  = (const float*)d_in[0];
    const float* aW1 = (const float*)d_in[1];
    const float* ab1 = (const float*)d_in[2];
    const float* aW2 = (const float*)d_in[3];
    const float* ab2 = (const float*)d_in[4];
    const float* aW3 = (const float*)d_in[5];
    // d_in[6] = ab3: constant shift, cancels in softmax
    const float* cW1 = (const float*)d_in[7];
    const float* cb1 = (const float*)d_in[8];
    const float* cW2 = (const float*)d_in[9];
    const float* cb2 = (const float*)d_in[10];
    const float* cW3 = (const float*)d_in[11];
    const float* cb3 = (const float*)d_in[12];
    // d_in[13] = K, known = 5000
    float* out = (float*)d_out;
    char* ws = (char*)d_ws;
    int*   pairs  = (int*)(ws + 0);                       // 640,000 B
    float* logits = (float*)(ws + 640000);                // 640,000 B
    float* g1     = (float*)(ws + 1280000);               // 131,072 B
    float* P1     = (float*)(ws + 1411072);               // 13,107,200 B (P2 contiguous after)
    float* P2     = (float*)(ws + 14518272);              // 13,107,200 B
    unsigned short* w2b = (unsigned short*)(ws + 27625472); // 2,097,152 B
    unsigned short* w1t = (unsigned short*)(ws + 29722624); // 1,048,576 B  (total ~30.8 MB)

    k_zero <<<313,  256, 0, stream>>>(out);
    k_pairs<<<32,   256, 0, stream>>>(ef, pairs);
    k_w1t  <<<256,  256, 0, stream>>>(aW1, w1t);
    k_w2b  <<<512,  256, 0, stream>>>(aW2, w2b);
    k_g1   <<<32,   256, 0, stream>>>(ef, aW1, ab1, g1);
    k_p    <<<1024, 256, 0, stream>>>(ef, w1t, P1);
    k_v    <<<32,   256, 0, stream>>>(ef, cW1, cb1, cW2, cb2, cW3, cb3, out);
    k_main <<<2528, 256, 0, stream>>>(pairs, g1, P1, P2, w2b, ab2, aW3, logits);
    k_soft <<<32,   256, 0, stream>>>(logits, pairs, out);
}

// Round 2
// 543.015 us; speedup vs baseline: 1.2594x; 1.2594x over previous
//
#include <hip/hip_runtime.h>
#include <stdint.h>

#define AS1 __attribute__((address_space(1)))
#define AS3 __attribute__((address_space(3)))

typedef __bf16 bf16x8 __attribute__((ext_vector_type(8)));
typedef float  f32x4  __attribute__((ext_vector_type(4)));
typedef int    i32x8  __attribute__((ext_vector_type(8)));
typedef float  f32x16 __attribute__((ext_vector_type(16)));

// tanh(x) = 1 - 2/(exp(2x)+1); exact at +/-inf.
__device__ __forceinline__ float tanh_fast(float x){
    float e = __expf(2.0f * x);
    return 1.0f - 2.0f / (e + 1.0f);
}

__device__ __forceinline__ unsigned short f2bf(float f){
    unsigned int u = __float_as_uint(f);
    u = (u + 0x7fffu + ((u >> 16) & 1u)) >> 16;   // RNE
    return (unsigned short)u;
}

// ---------------- zero the scatter output region ----------------
__global__ void k_zero(float* __restrict__ out){
    int i = blockIdx.x * 256 + threadIdx.x;
    if (i < 80000) ((float4*)out)[i] = make_float4(0.f, 0.f, 0.f, 0.f);
}

// ---------------- deterministic compaction of active mask positions ----------------
__global__ void k_pairs(const float* __restrict__ ef, int* __restrict__ pairs){
    int b = blockIdx.x, tid = threadIdx.x;
    __shared__ int s_base, s_woff[4], s_wc[4];
    if (tid == 0) s_base = 0;
    __syncthreads();
    int lane = tid & 63, w = tid >> 6;
    for (int ch = 0; ch < 40; ++ch){
        int pos = ch * 256 + tid;
        bool valid = false;
        if (pos < 10000){
            int r = pos / 100, c = pos - (pos / 100) * 100;
            valid = ef[(size_t)b * 35956 + (size_t)(1 + r) * 356 + 256 + c] != 0.0f;
        }
        unsigned long long bal = __ballot(valid);
        if (lane == 0) s_wc[w] = __popcll(bal);
        __syncthreads();
        if (tid == 0){
            int r = s_base;
            for (int q = 0; q < 4; ++q){ s_woff[q] = r; r += s_wc[q]; }
            s_base = r;
        }
        __syncthreads();
        if (valid){
            int rank = __popcll(bal & ((1ull << lane) - 1ull));
            int o = s_woff[w] + rank;
            if (o < 5000) pairs[b * 5000 + o] = pos;
        }
        __syncthreads();
    }
}

// ---------------- aW1[256:768] -> bf16, transposed [s][col][k] ----------------
__global__ void k_w1t(const float* __restrict__ aW1, unsigned short* __restrict__ w1t){
    int tid = blockIdx.x * 256 + threadIdx.x;          // 65536 threads
    int k8 = tid & 31, c = (tid >> 5) & 1023, s = tid >> 15;
    const float* src = aW1 + (size_t)(256 + s * 256 + k8 * 8) * 1024 + c;
    unsigned int* dst = (unsigned int*)(w1t + (size_t)tid * 8);
#pragma unroll
    for (int jj = 0; jj < 4; ++jj){
        unsigned short lo = f2bf(src[(size_t)(2 * jj) * 1024]);
        unsigned short hi = f2bf(src[(size_t)(2 * jj + 1) * 1024]);
        dst[jj] = (unsigned int)lo | ((unsigned int)hi << 16);
    }
}

// ---------------- aW2 -> fp8 e4m3, blocked into MFMA B-frag plane order ----------------
// layout: for ct in [0,32), kt in [0,16): 2048 B = [plane h=0: lane*16+j][plane h=1: ...]
// element (ct,kt,h,lane,j) = fp8(aW2[kt*64 + (lane>>5)*32 + h*16 + j][ct*32 + (lane&31)])
__global__ void k_w2b(const float* __restrict__ aW2, unsigned char* __restrict__ w2b){
    int tid = blockIdx.x * 256 + threadIdx.x;          // 32768 threads
    int lane = tid & 63, kt = (tid >> 6) & 15, ct = tid >> 10;
    int lh = lane >> 5, n = lane & 31;
    int kbase = kt * 64 + lh * 32;
    const float* src = aW2 + (size_t)kbase * 1024 + ct * 32 + n;
    unsigned char* dst = w2b + (size_t)(ct * 16 + kt) * 2048 + lane * 16;
#pragma unroll
    for (int h = 0; h < 2; ++h){
        unsigned int d[4];
#pragma unroll
        for (int jj = 0; jj < 4; ++jj){
            int j = h * 16 + jj * 4;
            int v = __builtin_amdgcn_cvt_pk_fp8_f32(src[(size_t)(j + 0) * 1024],
                                                    src[(size_t)(j + 1) * 1024], 0, false);
            v = __builtin_amdgcn_cvt_pk_fp8_f32(src[(size_t)(j + 2) * 1024],
                                                src[(size_t)(j + 3) * 1024], v, true);
            d[jj] = (unsigned int)v;
        }
        *(uint4*)(dst + h * 1024) = make_uint4(d[0], d[1], d[2], d[3]);
    }
}

// ---------------- g1[b][c] = g_b @ aW1[:256] + ab1 (fp32 exact) ----------------
__global__ void k_g1(const float* __restrict__ ef, const float* __restrict__ aW1,
                     const float* __restrict__ ab1, float* __restrict__ g1o){
    int b = blockIdx.x, t = threadIdx.x;
    __shared__ float gs[256];
    gs[t] = ef[(size_t)b * 35956 + t];
    __syncthreads();
    float a0 = 0.f, a1 = 0.f, a2 = 0.f, a3 = 0.f;
    for (int i = 0; i < 256; ++i){
        float gi = gs[i];
        const float* row = aW1 + (size_t)i * 1024;
        a0 += gi * row[t];       a1 += gi * row[t + 256];
        a2 += gi * row[t + 512]; a3 += gi * row[t + 768];
    }
    float* o = g1o + (size_t)b * 1024;
    o[t] = a0 + ab1[t];             o[t + 256] = a1 + ab1[t + 256];
    o[t + 512] = a2 + ab1[t + 512]; o[t + 768] = a3 + ab1[t + 768];
}

// ---------------- P{1,2}[b][node][c] = nodes_b @ aW1 slice; P1 rows += g1 ----------------
__global__ __launch_bounds__(256) void k_p(const float* __restrict__ ef,
        const unsigned short* __restrict__ w1t, float* __restrict__ P,
        const float* __restrict__ g1){
    __shared__ __align__(16) unsigned short an[112 * 264];
    int blk = blockIdx.x;
    int cb = blk & 15, s = (blk >> 4) & 1, b = blk >> 5;
    int t = threadIdx.x;
    for (int e = t; e < 25600; e += 256){            // stage nodes as bf16
        int row = e >> 8, col = e & 255;
        an[row * 264 + col] = f2bf(ef[(size_t)b * 35956 + (size_t)(1 + row) * 356 + col]);
    }
    for (int e = t; e < 3168; e += 256) an[26400 + e] = 0;  // zero pad rows 100..111
    __syncthreads();
    int w = t >> 6, lane = t & 63, quad = lane >> 4, n = lane & 15;
    int c = cb * 64 + w * 16 + n;
    f32x4 acc[7];
#pragma unroll
    for (int m = 0; m < 7; ++m){ f32x4 z = {0.f, 0.f, 0.f, 0.f}; acc[m] = z; }
    const bf16x8* wp = (const bf16x8*)(w1t + (size_t)(s * 1024 + c) * 256);
#pragma unroll
    for (int kt = 0; kt < 8; ++kt){
        bf16x8 bfr = wp[kt * 4 + quad];
#pragma unroll
        for (int m = 0; m < 7; ++m){
            const bf16x8* ap = (const bf16x8*)(an + (m * 16 + n) * 264 + kt * 32 + quad * 8);
            acc[m] = __builtin_amdgcn_mfma_f32_16x16x32_bf16(*ap, bfr, acc[m], 0, 0, 0);
        }
    }
    float addv = (s == 0) ? g1[(size_t)b * 1024 + c] : 0.0f;
    size_t base = (size_t)s * 3276800 + (size_t)b * 102400;
#pragma unroll
    for (int m = 0; m < 7; ++m){
        int r0 = m * 16 + quad * 4;
#pragma unroll
        for (int r = 0; r < 4; ++r){
            int row = r0 + r;
            if (row < 100) P[base + (size_t)row * 1024 + c] = acc[m][r] + addv;
        }
    }
}

// ---------------- value head (tiny, fp32) ----------------
__global__ void k_v(const float* __restrict__ ef,
                    const float* __restrict__ cW1, const float* __restrict__ cb1,
                    const float* __restrict__ cW2, const float* __restrict__ cb2,
                    const float* __restrict__ cW3, const float* __restrict__ cb3,
                    float* __restrict__ out){
    int b = blockIdx.x, t = threadIdx.x;
    __shared__ float gs[256], h1[512], h2[512], wred[4];
    gs[t] = ef[(size_t)b * 35956 + t];
    __syncthreads();
    for (int o = t; o < 512; o += 256){
        float a = cb1[o];
        for (int i = 0; i < 256; ++i) a += gs[i] * cW1[(size_t)i * 512 + o];
        h1[o] = tanh_fast(a);
    }
    __syncthreads();
    for (int o = t; o < 512; o += 256){
        float a = cb2[o];
        for (int i = 0; i < 512; ++i) a += h1[i] * cW2[(size_t)i * 512 + o];
        h2[o] = tanh_fast(a);
    }
    __syncthreads();
    float p = h2[t] * cW3[t] + h2[t + 256] * cW3[t + 256];
    for (int m = 32; m >= 1; m >>= 1) p += __shfl_xor(p, m);
    if ((t & 63) == 0) wred[t >> 6] = p;
    __syncthreads();
    if (t == 0) out[320000 + b] = wred[0] + wred[1] + wred[2] + wred[3] + cb3[0];
}

// ---------------- fused layer1-gather + fp8-MX layer2 GEMM + layer3 dot ----------------
// block = 4 waves, 32 rows/wave (128 rows/block); A (h, fp8) in registers;
// B streamed via LDS double-buffer (2 x 32KB), 32 col-tiles of 32 cols.
__global__ __launch_bounds__(256, 2) void k_main(
    const int* __restrict__ pairs,
    const float* __restrict__ P1, const float* __restrict__ P2,
    const unsigned char* __restrict__ w2b, const float* __restrict__ ab2,
    const float* __restrict__ aW3, float* __restrict__ logits)
{
    __shared__ __align__(16) unsigned char wbuf[2][32768];
    int b = blockIdx.x / 40, tile = blockIdx.x % 40;
    int t = threadIdx.x, w = t >> 6, lane = t & 63;
    int lrow = lane & 31, lh = lane >> 5;

    // prefetch ct=0 while phase 1 runs
    {
        const unsigned char* s = w2b + w * 8192 + lane * 16;
        unsigned char* d = &wbuf[0][0] + w * 8192 + lane * 16;
#pragma unroll
        for (int i = 0; i < 8; ++i)
            __builtin_amdgcn_global_load_lds((AS1 void*)(s + i * 1024),
                                             (AS3 void*)(d + i * 1024), 16, 0, 0);
    }

    int grow = tile * 128 + w * 32 + lrow;
    int pidx = pairs[b * 5000 + (grow < 5000 ? grow : 4999)];
    int i1 = pidx / 100, i2 = pidx - i1 * 100;
    const float* p1 = P1 + (((size_t)(b * 100 + i1)) << 10) + lh * 32;
    const float* p2 = P2 + (((size_t)(b * 100 + i2)) << 10) + lh * 32;

    // phase 1: h[m=lrow][k] = tanh(P1[i1][k] + P2[i2][k]), packed fp8.
    // af[kt] byte p (p=0..31) = k = kt*64 + lh*32 + p  (matches B plane order)
    i32x8 af[16];
#pragma unroll
    for (int kt = 0; kt < 16; ++kt){
        const float4* A  = (const float4*)(p1 + kt * 64);
        const float4* Bv = (const float4*)(p2 + kt * 64);
        int u[8];
#pragma unroll
        for (int q = 0; q < 8; ++q){
            float4 a = A[q], c = Bv[q];
            float t0 = tanh_fast(a.x + c.x);
            float t1 = tanh_fast(a.y + c.y);
            float t2 = tanh_fast(a.z + c.z);
            float t3 = tanh_fast(a.w + c.w);
            int v = __builtin_amdgcn_cvt_pk_fp8_f32(t0, t1, 0, false);
            v = __builtin_amdgcn_cvt_pk_fp8_f32(t2, t3, v, true);
            u[q] = v;
        }
        i32x8 f = {u[0], u[1], u[2], u[3], u[4], u[5], u[6], u[7]};
        af[kt] = f;
    }

    float prt[16];
#pragma unroll
    for (int r = 0; r < 16; ++r) prt[r] = 0.f;

    for (int ct = 0; ct < 32; ++ct){
        int cur = ct & 1;
        __syncthreads();                              // wbuf[cur] ready for all waves
        if (ct < 31){
            const unsigned char* s = w2b + (size_t)(ct + 1) * 32768 + w * 8192 + lane * 16;
            unsigned char* d = &wbuf[cur ^ 1][0] + w * 8192 + lane * 16;
#pragma unroll
            for (int i = 0; i < 8; ++i)
                __builtin_amdgcn_global_load_lds((AS1 void*)(s + i * 1024),
                                                 (AS3 void*)(d + i * 1024), 16, 0, 0);
        }
        const unsigned char* bb = &wbuf[cur][0] + lane * 16;
        f32x16 acc0, acc1;
#pragma unroll
        for (int r = 0; r < 16; ++r){ acc0[r] = 0.f; acc1[r] = 0.f; }
#pragma unroll
        for (int kt = 0; kt < 16; kt += 2){
            uint4 q0 = *(const uint4*)(bb + kt * 2048);
            uint4 q1 = *(const uint4*)(bb + kt * 2048 + 1024);
            uint4 q2 = *(const uint4*)(bb + (kt + 1) * 2048);
            uint4 q3 = *(const uint4*)(bb + (kt + 1) * 2048 + 1024);
            i32x8 b0 = {(int)q0.x, (int)q0.y, (int)q0.z, (int)q0.w,
                        (int)q1.x, (int)q1.y, (int)q1.z, (int)q1.w};
            i32x8 b1 = {(int)q2.x, (int)q2.y, (int)q2.z, (int)q2.w,
                        (int)q3.x, (int)q3.y, (int)q3.z, (int)q3.w};
            acc0 = __builtin_amdgcn_mfma_scale_f32_32x32x64_f8f6f4(
                       af[kt], b0, acc0, 0, 0, 0, 0x7F7F7F7F, 0, 0x7F7F7F7F);
            acc1 = __builtin_amdgcn_mfma_scale_f32_32x32x64_f8f6f4(
                       af[kt + 1], b1, acc1, 0, 0, 0, 0x7F7F7F7F, 0, 0x7F7F7F7F);
        }
        int c = ct * 32 + lrow;
        float w3 = aW3[c], bias = ab2[c];
#pragma unroll
        for (int r = 0; r < 16; ++r)
            prt[r] += tanh_fast(acc0[r] + acc1[r] + bias) * w3;
    }

    // reduce each reg's partial over the 32 cols (lanes within each half-wave)
#pragma unroll
    for (int r = 0; r < 16; ++r){
        float v = prt[r];
        v += __shfl_xor(v, 1); v += __shfl_xor(v, 2); v += __shfl_xor(v, 4);
        v += __shfl_xor(v, 8); v += __shfl_xor(v, 16);
        if (lrow == 0){
            int row = (r & 3) + 8 * (r >> 2) + 4 * lh;   // 32x32 C/D mapping
            int g = tile * 128 + w * 32 + row;
            if (g < 5000) logits[b * 5000 + g] = v;
        }
    }
}

// ---------------- softmax over K per batch + scatter into filled ----------------
__global__ void k_soft(const float* __restrict__ logits, const int* __restrict__ pairs,
                       float* __restrict__ out){
    int b = blockIdx.x, t = threadIdx.x;
    __shared__ float red[4];
    __shared__ float bmS, bsS;
    const float* lg = logits + b * 5000;
    float m = -1e30f;
    for (int j = t; j < 5000; j += 256) m = fmaxf(m, lg[j]);
    for (int s = 32; s >= 1; s >>= 1) m = fmaxf(m, __shfl_xor(m, s));
    if ((t & 63) == 0) red[t >> 6] = m;
    __syncthreads();
    if (t == 0) bmS = fmaxf(fmaxf(red[0], red[1]), fmaxf(red[2], red[3]));
    __syncthreads();
    float mm = bmS;
    float s = 0.f;
    for (int j = t; j < 5000; j += 256) s += __expf(lg[j] - mm);
    for (int k = 32; k >= 1; k >>= 1) s += __shfl_xor(s, k);
    if ((t & 63) == 0) red[t >> 6] = s;
    __syncthreads();
    if (t == 0) bsS = 1.0f / (red[0] + red[1] + red[2] + red[3]);
    __syncthreads();
    float inv = bsS;
    for (int j = t; j < 5000; j += 256){
        int pos = pairs[b * 5000 + j];
        out[(size_t)b * 10000 + pos] = __expf(lg[j] - mm) * inv;
    }
}

extern "C" void kernel_launch(void* const* d_in, const int* in_sizes, int n_in,
                              void* d_out, int out_size, void* d_ws, size_t ws_size,
                              hipStream_t stream) {
    (void)in_sizes; (void)n_in; (void)out_size; (void)ws_size;
    const float* ef  = (const float*)d_in[0];
    const float* aW1 = (const float*)d_in[1];
    const float* ab1 = (const float*)d_in[2];
    const float* aW2 = (const float*)d_in[3];
    const float* ab2 = (const float*)d_in[4];
    const float* aW3 = (const float*)d_in[5];
    // d_in[6] = ab3: constant shift, cancels in softmax
    const float* cW1 = (const float*)d_in[7];
    const float* cb1 = (const float*)d_in[8];
    const float* cW2 = (const float*)d_in[9];
    const float* cb2 = (const float*)d_in[10];
    const float* cW3 = (const float*)d_in[11];
    const float* cb3 = (const float*)d_in[12];
    // d_in[13] = K, known = 5000
    float* out = (float*)d_out;
    char* ws = (char*)d_ws;
    int*   pairs  = (int*)(ws + 0);                         // 640,000 B
    float* logits = (float*)(ws + 640000);                  // 640,000 B
    float* g1     = (float*)(ws + 1280000);                 // 131,072 B
    float* P1     = (float*)(ws + 1411072);                 // 13,107,200 B
    float* P2     = (float*)(ws + 14518272);                // 13,107,200 B
    unsigned char*  w2b = (unsigned char*)(ws + 27625472);  // 1,048,576 B (fp8 blocked)
    unsigned short* w1t = (unsigned short*)(ws + 29722624); // 1,048,576 B

    k_zero <<<313,  256, 0, stream>>>(out);
    k_pairs<<<32,   256, 0, stream>>>(ef, pairs);
    k_w1t  <<<256,  256, 0, stream>>>(aW1, w1t);
    k_w2b  <<<128,  256, 0, stream>>>(aW2, w2b);
    k_g1   <<<32,   256, 0, stream>>>(ef, aW1, ab1, g1);
    k_p    <<<1024, 256, 0, stream>>>(ef, w1t, P1, g1);
    k_v    <<<32,   256, 0, stream>>>(ef, cW1, cb1, cW2, cb2, cW3, cb3, out);
    k_main <<<1280, 256, 0, stream>>>(pairs, P1, P2, w2b, ab2, aW3, logits);
    k_soft <<<32,   256, 0, stream>>>(logits, pairs, out);
}